// Round 2
// baseline (1416.151 us; speedup 1.0000x reference)
//
#include <hip/hip_runtime.h>
#include <hip/hip_bf16.h>
#include <math.h>

// ConvBlockFD R4:
// - conv kernels: 512-thread blocks (8 waves = 2 co-halves x 4 row-groups) share one
//   LDS x-tile -> halves staging work + barriers per output vs 4-co-block grid.
// - conv1 now uses mfma(wf, xf) (D=[co][px], the verified MODE1 mapping) so the 4
//   acc components per frag are CONSECUTIVE co -> packed 8B bf16 stores (was 64x 2B).
// - GAP fusion: layer-1 GAP folded into transpose (x read once), layer-2 GAP folded
//   into conv1 epilogue (post-ReLU fp32, pre-rounding) via shfl-reduce + atomicAdd.
//   Removes fd_gap / gap_t_part / gap_t_reduce (268 MB HBM reads + 3 dispatches).
// - fd_attn takes a scale arg (gap buffers hold raw sums; scale = 1/HW).

#define K_NUM 4
typedef __attribute__((ext_vector_type(8))) short short8;   // 8 bf16 = 4 VGPR
typedef __attribute__((ext_vector_type(4))) short s16x4;    // 4 bf16 = 8B store
typedef __attribute__((ext_vector_type(4))) float f32x4;    // MFMA C/D frag

__device__ inline float bf2f(short s) {
  unsigned u = ((unsigned)(unsigned short)s) << 16;
  return __uint_as_float(u);
}
__device__ inline short f2bf(float f) {
  __hip_bfloat16 h = __float2bfloat16(f);
  return (short)*reinterpret_cast<unsigned short*>(&h);
}

// ---------------- attention MLP + softmax (gap holds raw sums; gscale = 1/HW) ----
__global__ void fd_attn_kernel(const float* __restrict__ gap, int C, int Hd, float gscale,
                               const float* __restrict__ w1, const float* __restrict__ b1,
                               const float* __restrict__ w2, const float* __restrict__ b2,
                               float* __restrict__ attn) {
  int b = blockIdx.x, j = threadIdx.x;
  __shared__ float h[64];
  __shared__ float z[K_NUM];
  if (j < Hd) {
    float s = b1[j];
    const float* g = gap + (size_t)b * C;
    for (int c = 0; c < C; ++c) s = fmaf(g[c] * gscale, w1[c * Hd + j], s);
    h[j] = fmaxf(s, 0.f);
  }
  __syncthreads();
  if (j < K_NUM) {
    float s = b2[j];
    for (int c = 0; c < Hd; ++c) s = fmaf(h[c], w2[c * K_NUM + j], s);
    z[j] = s;
  }
  __syncthreads();
  if (j == 0) {
    float m = z[0];
    for (int k = 1; k < K_NUM; ++k) m = fmaxf(m, z[k]);
    float e[K_NUM], sum = 0.f;
    for (int k = 0; k < K_NUM; ++k) { e[k] = expf(z[k] - m); sum += e[k]; }
    for (int k = 0; k < K_NUM; ++k) attn[b * K_NUM + k] = e[k] / sum;
  }
}

// ---------------- synthesis: irfft2 + attention mix -> wd_t[b][9][ci/8][co][8] bf16 ----
// ci-fastest mapping: consecutive lanes read consecutive 24B coeff chunks (coalesced).
__global__ void fd_synth_t_kernel(const float* __restrict__ wfr, const float* __restrict__ wfi,
                                  const float* __restrict__ attn, short* __restrict__ wdt,
                                  int B, int CO, int CI) {
  size_t gid = (size_t)blockIdx.x * blockDim.x + threadIdx.x;
  size_t total = (size_t)B * CI * CO;
  if (gid >= total) return;
  int ci = (int)(gid % CI);
  size_t t = gid / CI;
  int co = (int)(t % CO);
  int b = (int)(t / CO);

  float a[K_NUM];
  for (int k = 0; k < K_NUM; ++k) a[k] = attn[b * K_NUM + k];

  float Fr[3][2], Fi[3][2];
  for (int u = 0; u < 3; ++u) for (int v = 0; v < 2; ++v) { Fr[u][v] = 0.f; Fi[u][v] = 0.f; }
  for (int k = 0; k < K_NUM; ++k) {
    size_t base = ((((size_t)k * CO + co) * CI + ci) * 3) * 2;
    const float* pr = wfr + base;
    const float* pi = wfi + base;
    float ak = a[k];
    for (int u = 0; u < 3; ++u)
      for (int v = 0; v < 2; ++v) {
        Fr[u][v] = fmaf(ak, pr[u * 2 + v], Fr[u][v]);
        Fi[u][v] = fmaf(ak, pi[u * 2 + v], Fi[u][v]);
      }
  }

  const float CS[3] = {1.f, -0.5f, -0.5f};
  const float SN[3] = {0.f, 0.8660254037844386f, -0.8660254037844386f};
  float outv[9];
  for (int ai = 0; ai < 3; ++ai) {
    float Gr[2], Gi[2];
    for (int v = 0; v < 2; ++v) {
      float gr = 0.f, gi = 0.f;
      for (int u = 0; u < 3; ++u) {
        int idx = (u * ai) % 3;
        gr += Fr[u][v] * CS[idx] - Fi[u][v] * SN[idx];
        gi += Fr[u][v] * SN[idx] + Fi[u][v] * CS[idx];
      }
      Gr[v] = gr * (1.f / 3.f);
      Gi[v] = gi * (1.f / 3.f);
    }
    for (int bi = 0; bi < 3; ++bi)
      outv[ai * 3 + bi] = (Gr[0] + 2.f * (Gr[1] * CS[bi] - Gi[1] * SN[bi])) * (1.f / 3.f);
  }
  int ci8 = ci >> 3, cil = ci & 7;
  for (int s = 0; s < 9; ++s)
    wdt[((((size_t)b * 9 + s) * (CI / 8) + ci8) * CO + co) * 8 + cil] = f2bf(outv[s]);
}

// ---------------- transpose fp32 NCHW -> bf16 channels-last, fused layer-1 GAP ----
__global__ __launch_bounds__(256) void transpose_bf16_kernel(
    const float* __restrict__ in, short* __restrict__ out, int C,
    float* __restrict__ gap1) {
  const int HW = 16384;
  __shared__ short t[64 * 40];
  int tid = threadIdx.x;
  int px0 = blockIdx.x * 64, c0 = blockIdx.y * 32, b = blockIdx.z;
  int px = tid & 63, cb = tid >> 6;      // wave cb handles c = {cb, 4+cb, ..., 28+cb}
  float sums[8];
#pragma unroll
  for (int i = 0; i < 8; ++i) {
    int c = i * 4 + cb;
    float v = in[((size_t)b * C + c0 + c) * HW + px0 + px];
    t[px * 40 + c] = f2bf(v);
    sums[i] = v;
  }
  __syncthreads();
  int px2 = tid >> 2, g = tid & 3;
  short8 v = *(const short8*)(t + px2 * 40 + g * 8);
  *(short8*)(out + ((size_t)b * HW + px0 + px2) * C + c0 + g * 8) = v;
  // reduce 64-px partials per channel across the wave, one atomic per (wave, c)
#pragma unroll
  for (int m = 1; m <= 32; m <<= 1)
#pragma unroll
    for (int i = 0; i < 8; ++i) sums[i] += __shfl_xor(sums[i], m, 64);
  if ((tid & 63) == 0)
#pragma unroll
    for (int i = 0; i < 8; ++i)
      atomicAdd(gap1 + (size_t)b * C + c0 + i * 4 + cb, sums[i]);
}

// ---------------- MFMA conv: 9 shift-GEMMs, 16x16x32 bf16 ----------------
// Block: 512 threads = 8 waves (wc = wave>>2 picks co-half, wy = wave&3 picks row group).
// Block tile: 128 co x 256 px (16x16 spatial); per wave 64 co x 64 px (4x4 frags).
// Compute: mfma(wf, xf) -> D[m=co][n=px-col]; lane: co = l4*4+r (per cf), col = l15.
// MODE 0 (conv1): packed s16x4 bf16 channels-last store + fused layer-2 GAP atomics.
// MODE 1 (conv2): fp32 NCHW store.
template <int CI, int MODE>
__global__ __launch_bounds__(512) void conv_mfma_kernel(
    const short* __restrict__ xin,   // [B][HW][CI] bf16
    const short* __restrict__ wdt,   // [B][9][CI/8][256][8] bf16
    const float* __restrict__ bias,  // [256]
    short* __restrict__ yout_t,      // MODE0 out
    float* __restrict__ yout_f,      // MODE1 out
    float* __restrict__ gap_out) {   // MODE0: layer-2 GAP accumulator [B][256]
  const int H = 128, W = 128, HW = H * W, CO = 256;
  const int NKC = CI / 32;
  __shared__ short xs[18 * 18 * 40];  // [px 18x18][ci 32 pad 40] bf16

  const int tid = threadIdx.x;
  const int w = tid >> 6;
  const int wy = w & 3, wc = w >> 2;
  const int lane = tid & 63;
  const int l15 = lane & 15, l4 = lane >> 4;
  const int tx0 = (blockIdx.x & 7) * 16, ty0 = (blockIdx.x >> 3) * 16;
  const int cob = blockIdx.y * 128 + wc * 64;
  const int b = blockIdx.z;

  f32x4 acc[4][4];
#pragma unroll
  for (int i = 0; i < 4; ++i)
#pragma unroll
    for (int j = 0; j < 4; ++j)
      acc[i][j] = (f32x4){0.f, 0.f, 0.f, 0.f};

  for (int kc = 0; kc < NKC; ++kc) {
    __syncthreads();
    // stage x tile: 18x18 px halo x 32 ci -> 1296 16B chunks over 512 threads
#pragma unroll
    for (int i = 0; i < 3; ++i) {
      int idx = i * 512 + tid;
      if (idx < 1296) {
        int pxi = idx >> 2, g = idx & 3;
        int r = pxi / 18, c = pxi - r * 18;
        int gy = ty0 + r - 1, gx = tx0 + c - 1;
        short8 v = {0, 0, 0, 0, 0, 0, 0, 0};
        if ((unsigned)gy < (unsigned)H && (unsigned)gx < (unsigned)W)
          v = *(const short8*)(xin + ((size_t)b * HW + gy * W + gx) * CI + kc * 32 + g * 8);
        *(short8*)(xs + pxi * 40 + g * 8) = v;
      }
    }
    __syncthreads();

#pragma unroll
    for (int dc = 0; dc < 3; ++dc) {
      // x frags: 6 distinct rows cover all (nf, dr) pairs for this wave's row group
      short8 xf[6];
#pragma unroll
      for (int rr = 0; rr < 6; ++rr)
        xf[rr] = *(const short8*)(xs + ((4 * wy + rr) * 18 + l15 + dc) * 40 + l4 * 8);
      // w frags for all 3 dr of this dc (from L2, lane-contiguous 16B)
      short8 wf[3][4];
#pragma unroll
      for (int dr = 0; dr < 3; ++dr) {
        const short* wp = wdt + ((((size_t)b * 9 + dr * 3 + dc) * (CI / 8) + kc * 4 + l4) * CO + cob + l15) * 8;
#pragma unroll
        for (int cf = 0; cf < 4; ++cf)
          wf[dr][cf] = *(const short8*)(wp + cf * 128);
      }
#pragma unroll
      for (int dr = 0; dr < 3; ++dr)
#pragma unroll
        for (int nf = 0; nf < 4; ++nf)
#pragma unroll
          for (int cf = 0; cf < 4; ++cf)
            acc[nf][cf] = __builtin_amdgcn_mfma_f32_16x16x32_bf16(
                wf[dr][cf], xf[nf + dr], acc[nf][cf], 0, 0, 0);
    }
  }

  if (MODE == 0) {
    // packed bf16 channels-last store (r = consecutive co) + fused GAP partials
#pragma unroll
    for (int cf = 0; cf < 4; ++cf) {
      float bs[4], gs[4];
#pragma unroll
      for (int r = 0; r < 4; ++r) { bs[r] = bias[cob + cf * 16 + l4 * 4 + r]; gs[r] = 0.f; }
#pragma unroll
      for (int nf = 0; nf < 4; ++nf) {
        int row = ty0 + 4 * wy + nf, col = tx0 + l15;
        s16x4 pk;
#pragma unroll
        for (int r = 0; r < 4; ++r) {
          float v = fmaxf(acc[nf][cf][r] + bs[r], 0.f);
          pk[r] = f2bf(v);
          gs[r] += v;
        }
        *(s16x4*)(yout_t + ((size_t)b * HW + (size_t)row * W + col) * CO + cob + cf * 16 + l4 * 4) = pk;
      }
      // 16 lanes (same l4, varying l15) share the same co's -> reduce over px
#pragma unroll
      for (int m = 1; m <= 8; m <<= 1)
#pragma unroll
        for (int r = 0; r < 4; ++r) gs[r] += __shfl_xor(gs[r], m, 64);
      if (l15 == 0)
#pragma unroll
        for (int r = 0; r < 4; ++r)
          atomicAdd(gap_out + (size_t)b * 256 + cob + cf * 16 + l4 * 4 + r, gs[r]);
    }
  } else {
    // fp32 NCHW store
#pragma unroll
    for (int cf = 0; cf < 4; ++cf) {
#pragma unroll
      for (int r = 0; r < 4; ++r) {
        int co = cob + cf * 16 + l4 * 4 + r;
        float bs = bias[co];
#pragma unroll
        for (int nf = 0; nf < 4; ++nf) {
          int row = ty0 + 4 * wy + nf;
          int col = tx0 + l15;
          yout_f[((size_t)b * CO + co) * HW + (size_t)row * W + col] =
              fmaxf(acc[nf][cf][r] + bs, 0.f);
        }
      }
    }
  }
}

extern "C" void kernel_launch(void* const* d_in, const int* in_sizes, int n_in,
                              void* d_out, int out_size, void* d_ws, size_t ws_size,
                              hipStream_t stream) {
  const int B = 16, CIN = 128, COUT = 256, H = 128, W = 128, HW = H * W;

  const float* x    = (const float*)d_in[0];
  const float* w1fr = (const float*)d_in[1];
  const float* w1fi = (const float*)d_in[2];
  const float* b1   = (const float*)d_in[3];
  const float* a1w1 = (const float*)d_in[4];
  const float* a1b1 = (const float*)d_in[5];
  const float* a1w2 = (const float*)d_in[6];
  const float* a1b2 = (const float*)d_in[7];
  const float* w2fr = (const float*)d_in[8];
  const float* w2fi = (const float*)d_in[9];
  const float* b2   = (const float*)d_in[10];
  const float* a2w1 = (const float*)d_in[11];
  const float* a2b1 = (const float*)d_in[12];
  const float* a2w2 = (const float*)d_in[13];
  const float* a2b2 = (const float*)d_in[14];
  float* outf = (float*)d_out;

  // xt (67MB bf16) parked in d_out: read only by conv1; conv2 overwrites d_out last.
  short* xt = (short*)d_out;

  char* wsb = (char*)d_ws;
  short* y1t  = (short*)wsb;                                   // 134,217,728 B
  short* wdt  = (short*)(wsb + 134217728);                     //  18,874,368 B
  float* gap1 = (float*)(wsb + 134217728 + 18874368);          //       8,192 B (B*CIN)
  float* gap2 = (float*)(wsb + 134217728 + 18874368 + 8192);   //      16,384 B (B*COUT)
  float* attn = (float*)(wsb + 134217728 + 18874368 + 8192 + 16384); // 256 B

  const float gsc = 1.f / (float)HW;

  // zero both GAP accumulators (atomically accumulated by fused kernels)
  hipMemsetAsync(gap1, 0, (size_t)B * (CIN + COUT) * sizeof(float), stream);

  // ---- layer 1 ----
  transpose_bf16_kernel<<<dim3(HW / 64, CIN / 32, B), 256, 0, stream>>>(x, xt, CIN, gap1);
  fd_attn_kernel<<<B, 64, 0, stream>>>(gap1, CIN, CIN / 4, gsc, a1w1, a1b1, a1w2, a1b2, attn);
  fd_synth_t_kernel<<<(B * CIN * COUT) / 256, 256, 0, stream>>>(w1fr, w1fi, attn, wdt, B, COUT, CIN);
  conv_mfma_kernel<128, 0><<<dim3(64, 2, 16), 512, 0, stream>>>(xt, wdt, b1, y1t, nullptr, gap2);

  // ---- layer 2 ----
  fd_attn_kernel<<<B, 64, 0, stream>>>(gap2, COUT, COUT / 4, gsc, a2w1, a2b1, a2w2, a2b2, attn);
  fd_synth_t_kernel<<<(B * COUT * COUT) / 256, 256, 0, stream>>>(w2fr, w2fi, attn, wdt, B, COUT, COUT);
  conv_mfma_kernel<256, 1><<<dim3(64, 2, 16), 512, 0, stream>>>(y1t, wdt, b2, nullptr, outf, nullptr);
}

// Round 3
// 1390.589 us; speedup vs baseline: 1.0184x; 1.0184x over previous
//
#include <hip/hip_runtime.h>
#include <hip/hip_bf16.h>
#include <math.h>

// ConvBlockFD R5:
// - R4's conv1 store regression fixed: epilogue stages each wave's 16px x 64co tile
//   in per-wave-private LDS (reusing xs after one barrier), reads back as short8 so
//   8-lane groups store 128B-contiguous channels-last chunks (global_store_dwordx4).
//   R4 had consecutive lanes at 512B stride (8B scattered stores) -> ~630us conv1.
// - Keeps: 512-thread conv blocks (VGPR 68), GAP fusion (layer1 in transpose,
//   layer2 in conv1 epilogue), ci-fastest synth, packed MODE1 conv2.

#define K_NUM 4
typedef __attribute__((ext_vector_type(8))) short short8;   // 8 bf16 = 4 VGPR
typedef __attribute__((ext_vector_type(4))) short s16x4;    // 4 bf16 = 8B
typedef __attribute__((ext_vector_type(4))) float f32x4;    // MFMA C/D frag

__device__ inline float bf2f(short s) {
  unsigned u = ((unsigned)(unsigned short)s) << 16;
  return __uint_as_float(u);
}
__device__ inline short f2bf(float f) {
  __hip_bfloat16 h = __float2bfloat16(f);
  return (short)*reinterpret_cast<unsigned short*>(&h);
}

// ---------------- attention MLP + softmax (gap holds raw sums; gscale = 1/HW) ----
__global__ void fd_attn_kernel(const float* __restrict__ gap, int C, int Hd, float gscale,
                               const float* __restrict__ w1, const float* __restrict__ b1,
                               const float* __restrict__ w2, const float* __restrict__ b2,
                               float* __restrict__ attn) {
  int b = blockIdx.x, j = threadIdx.x;
  __shared__ float h[64];
  __shared__ float z[K_NUM];
  if (j < Hd) {
    float s = b1[j];
    const float* g = gap + (size_t)b * C;
    for (int c = 0; c < C; ++c) s = fmaf(g[c] * gscale, w1[c * Hd + j], s);
    h[j] = fmaxf(s, 0.f);
  }
  __syncthreads();
  if (j < K_NUM) {
    float s = b2[j];
    for (int c = 0; c < Hd; ++c) s = fmaf(h[c], w2[c * K_NUM + j], s);
    z[j] = s;
  }
  __syncthreads();
  if (j == 0) {
    float m = z[0];
    for (int k = 1; k < K_NUM; ++k) m = fmaxf(m, z[k]);
    float e[K_NUM], sum = 0.f;
    for (int k = 0; k < K_NUM; ++k) { e[k] = expf(z[k] - m); sum += e[k]; }
    for (int k = 0; k < K_NUM; ++k) attn[b * K_NUM + k] = e[k] / sum;
  }
}

// ---------------- synthesis: irfft2 + attention mix -> wd_t[b][9][ci/8][co][8] bf16 ----
// ci-fastest mapping: consecutive lanes read consecutive 24B coeff chunks (coalesced).
__global__ void fd_synth_t_kernel(const float* __restrict__ wfr, const float* __restrict__ wfi,
                                  const float* __restrict__ attn, short* __restrict__ wdt,
                                  int B, int CO, int CI) {
  size_t gid = (size_t)blockIdx.x * blockDim.x + threadIdx.x;
  size_t total = (size_t)B * CI * CO;
  if (gid >= total) return;
  int ci = (int)(gid % CI);
  size_t t = gid / CI;
  int co = (int)(t % CO);
  int b = (int)(t / CO);

  float a[K_NUM];
  for (int k = 0; k < K_NUM; ++k) a[k] = attn[b * K_NUM + k];

  float Fr[3][2], Fi[3][2];
  for (int u = 0; u < 3; ++u) for (int v = 0; v < 2; ++v) { Fr[u][v] = 0.f; Fi[u][v] = 0.f; }
  for (int k = 0; k < K_NUM; ++k) {
    size_t base = ((((size_t)k * CO + co) * CI + ci) * 3) * 2;
    const float* pr = wfr + base;
    const float* pi = wfi + base;
    float ak = a[k];
    for (int u = 0; u < 3; ++u)
      for (int v = 0; v < 2; ++v) {
        Fr[u][v] = fmaf(ak, pr[u * 2 + v], Fr[u][v]);
        Fi[u][v] = fmaf(ak, pi[u * 2 + v], Fi[u][v]);
      }
  }

  const float CS[3] = {1.f, -0.5f, -0.5f};
  const float SN[3] = {0.f, 0.8660254037844386f, -0.8660254037844386f};
  float outv[9];
  for (int ai = 0; ai < 3; ++ai) {
    float Gr[2], Gi[2];
    for (int v = 0; v < 2; ++v) {
      float gr = 0.f, gi = 0.f;
      for (int u = 0; u < 3; ++u) {
        int idx = (u * ai) % 3;
        gr += Fr[u][v] * CS[idx] - Fi[u][v] * SN[idx];
        gi += Fr[u][v] * SN[idx] + Fi[u][v] * CS[idx];
      }
      Gr[v] = gr * (1.f / 3.f);
      Gi[v] = gi * (1.f / 3.f);
    }
    for (int bi = 0; bi < 3; ++bi)
      outv[ai * 3 + bi] = (Gr[0] + 2.f * (Gr[1] * CS[bi] - Gi[1] * SN[bi])) * (1.f / 3.f);
  }
  int ci8 = ci >> 3, cil = ci & 7;
  for (int s = 0; s < 9; ++s)
    wdt[((((size_t)b * 9 + s) * (CI / 8) + ci8) * CO + co) * 8 + cil] = f2bf(outv[s]);
}

// ---------------- transpose fp32 NCHW -> bf16 channels-last, fused layer-1 GAP ----
__global__ __launch_bounds__(256) void transpose_bf16_kernel(
    const float* __restrict__ in, short* __restrict__ out, int C,
    float* __restrict__ gap1) {
  const int HW = 16384;
  __shared__ short t[64 * 40];
  int tid = threadIdx.x;
  int px0 = blockIdx.x * 64, c0 = blockIdx.y * 32, b = blockIdx.z;
  int px = tid & 63, cb = tid >> 6;      // wave cb handles c = {cb, 4+cb, ..., 28+cb}
  float sums[8];
#pragma unroll
  for (int i = 0; i < 8; ++i) {
    int c = i * 4 + cb;
    float v = in[((size_t)b * C + c0 + c) * HW + px0 + px];
    t[px * 40 + c] = f2bf(v);
    sums[i] = v;
  }
  __syncthreads();
  int px2 = tid >> 2, g = tid & 3;
  short8 v = *(const short8*)(t + px2 * 40 + g * 8);
  *(short8*)(out + ((size_t)b * HW + px0 + px2) * C + c0 + g * 8) = v;
  // reduce 64-px partials per channel across the wave, one atomic per (wave, c)
#pragma unroll
  for (int m = 1; m <= 32; m <<= 1)
#pragma unroll
    for (int i = 0; i < 8; ++i) sums[i] += __shfl_xor(sums[i], m, 64);
  if ((tid & 63) == 0)
#pragma unroll
    for (int i = 0; i < 8; ++i)
      atomicAdd(gap1 + (size_t)b * C + c0 + i * 4 + cb, sums[i]);
}

// ---------------- MFMA conv: 9 shift-GEMMs, 16x16x32 bf16 ----------------
// Block: 512 threads = 8 waves (wc = wave>>2 picks co-half, wy = wave&3 picks row group).
// Block tile: 128 co x 256 px (16x16 spatial); per wave 64 co x 64 px (4x4 frags).
// Compute: mfma(wf, xf) -> D[m=co][n=px-col]; lane: co = cf*16 + l4*4 + r, col = l15.
// MODE 0 (conv1): LDS-transposed epilogue -> short8 stores (128B contiguous per px),
//   + fused layer-2 GAP atomics. MODE 1 (conv2): fp32 NCHW store.
template <int CI, int MODE>
__global__ __launch_bounds__(512) void conv_mfma_kernel(
    const short* __restrict__ xin,   // [B][HW][CI] bf16
    const short* __restrict__ wdt,   // [B][9][CI/8][256][8] bf16
    const float* __restrict__ bias,  // [256]
    short* __restrict__ yout_t,      // MODE0 out
    float* __restrict__ yout_f,      // MODE1 out
    float* __restrict__ gap_out) {   // MODE0: layer-2 GAP accumulator [B][256]
  const int H = 128, W = 128, HW = H * W, CO = 256;
  const int NKC = CI / 32;
  __shared__ short xs[18 * 18 * 40];  // [px 18x18][ci 32 pad 40] bf16

  const int tid = threadIdx.x;
  const int w = tid >> 6;
  const int wy = w & 3, wc = w >> 2;
  const int lane = tid & 63;
  const int l15 = lane & 15, l4 = lane >> 4;
  const int tx0 = (blockIdx.x & 7) * 16, ty0 = (blockIdx.x >> 3) * 16;
  const int cob = blockIdx.y * 128 + wc * 64;
  const int b = blockIdx.z;

  f32x4 acc[4][4];
#pragma unroll
  for (int i = 0; i < 4; ++i)
#pragma unroll
    for (int j = 0; j < 4; ++j)
      acc[i][j] = (f32x4){0.f, 0.f, 0.f, 0.f};

  for (int kc = 0; kc < NKC; ++kc) {
    __syncthreads();
    // stage x tile: 18x18 px halo x 32 ci -> 1296 16B chunks over 512 threads
#pragma unroll
    for (int i = 0; i < 3; ++i) {
      int idx = i * 512 + tid;
      if (idx < 1296) {
        int pxi = idx >> 2, g = idx & 3;
        int r = pxi / 18, c = pxi - r * 18;
        int gy = ty0 + r - 1, gx = tx0 + c - 1;
        short8 v = {0, 0, 0, 0, 0, 0, 0, 0};
        if ((unsigned)gy < (unsigned)H && (unsigned)gx < (unsigned)W)
          v = *(const short8*)(xin + ((size_t)b * HW + gy * W + gx) * CI + kc * 32 + g * 8);
        *(short8*)(xs + pxi * 40 + g * 8) = v;
      }
    }
    __syncthreads();

#pragma unroll
    for (int dc = 0; dc < 3; ++dc) {
      // x frags: 6 distinct rows cover all (nf, dr) pairs for this wave's row group
      short8 xf[6];
#pragma unroll
      for (int rr = 0; rr < 6; ++rr)
        xf[rr] = *(const short8*)(xs + ((4 * wy + rr) * 18 + l15 + dc) * 40 + l4 * 8);
      // w frags for all 3 dr of this dc (from L2, lane-contiguous 16B)
      short8 wf[3][4];
#pragma unroll
      for (int dr = 0; dr < 3; ++dr) {
        const short* wp = wdt + ((((size_t)b * 9 + dr * 3 + dc) * (CI / 8) + kc * 4 + l4) * CO + cob + l15) * 8;
#pragma unroll
        for (int cf = 0; cf < 4; ++cf)
          wf[dr][cf] = *(const short8*)(wp + cf * 128);
      }
#pragma unroll
      for (int dr = 0; dr < 3; ++dr)
#pragma unroll
        for (int nf = 0; nf < 4; ++nf)
#pragma unroll
          for (int cf = 0; cf < 4; ++cf)
            acc[nf][cf] = __builtin_amdgcn_mfma_f32_16x16x32_bf16(
                wf[dr][cf], xf[nf + dr], acc[nf][cf], 0, 0, 0);
    }
  }

  if (MODE == 0) {
    // Wave-private LDS transpose epilogue. After this barrier each wave owns a
    // disjoint 16px x 68-short region of xs (pad 68 breaks bank alignment).
    __syncthreads();
    short* st = xs + w * 1104;  // 16*68=1088 shorts used, 1104 stride; 8*1104=8832 < 12960
    float gs[4][4];
#pragma unroll
    for (int cf = 0; cf < 4; ++cf)
#pragma unroll
      for (int r = 0; r < 4; ++r) gs[cf][r] = 0.f;
    float bs[4][4];
#pragma unroll
    for (int cf = 0; cf < 4; ++cf)
#pragma unroll
      for (int r = 0; r < 4; ++r) bs[cf][r] = bias[cob + cf * 16 + l4 * 4 + r];

#pragma unroll
    for (int nf = 0; nf < 4; ++nf) {
      int row = ty0 + 4 * wy + nf;
      // write: lane (l15=px, l4) stores 4 consecutive co per cf
#pragma unroll
      for (int cf = 0; cf < 4; ++cf) {
        s16x4 pk;
#pragma unroll
        for (int r = 0; r < 4; ++r) {
          float v = fmaxf(acc[nf][cf][r] + bs[cf][r], 0.f);
          pk[r] = f2bf(v);
          gs[cf][r] += v;
        }
        *(s16x4*)(st + l15 * 68 + cf * 16 + l4 * 4) = pk;
      }
      // read+store: 8 lanes per px, each lane 16B -> 128B contiguous per px
#pragma unroll
      for (int half = 0; half < 2; ++half) {
        int p = half * 8 + (lane >> 3);
        int ch = (lane & 7) * 8;
        short8 vv = *(const short8*)(st + p * 68 + ch);
        *(short8*)(yout_t + ((size_t)b * HW + (size_t)row * W + tx0 + p) * CO + cob + ch) = vv;
      }
    }
    // fused layer-2 GAP: reduce over px (l15 dim), one atomic per co
#pragma unroll
    for (int m = 1; m <= 8; m <<= 1)
#pragma unroll
      for (int cf = 0; cf < 4; ++cf)
#pragma unroll
        for (int r = 0; r < 4; ++r) gs[cf][r] += __shfl_xor(gs[cf][r], m, 64);
    if (l15 == 0)
#pragma unroll
      for (int cf = 0; cf < 4; ++cf)
#pragma unroll
        for (int r = 0; r < 4; ++r)
          atomicAdd(gap_out + (size_t)b * 256 + cob + cf * 16 + l4 * 4 + r, gs[cf][r]);
  } else {
    // fp32 NCHW store: 16 lanes (l15) cover 64B contiguous per (co,row)
#pragma unroll
    for (int cf = 0; cf < 4; ++cf) {
#pragma unroll
      for (int r = 0; r < 4; ++r) {
        int co = cob + cf * 16 + l4 * 4 + r;
        float bs = bias[co];
#pragma unroll
        for (int nf = 0; nf < 4; ++nf) {
          int row = ty0 + 4 * wy + nf;
          int col = tx0 + l15;
          yout_f[((size_t)b * CO + co) * HW + (size_t)row * W + col] =
              fmaxf(acc[nf][cf][r] + bs, 0.f);
        }
      }
    }
  }
}

extern "C" void kernel_launch(void* const* d_in, const int* in_sizes, int n_in,
                              void* d_out, int out_size, void* d_ws, size_t ws_size,
                              hipStream_t stream) {
  const int B = 16, CIN = 128, COUT = 256, H = 128, W = 128, HW = H * W;

  const float* x    = (const float*)d_in[0];
  const float* w1fr = (const float*)d_in[1];
  const float* w1fi = (const float*)d_in[2];
  const float* b1   = (const float*)d_in[3];
  const float* a1w1 = (const float*)d_in[4];
  const float* a1b1 = (const float*)d_in[5];
  const float* a1w2 = (const float*)d_in[6];
  const float* a1b2 = (const float*)d_in[7];
  const float* w2fr = (const float*)d_in[8];
  const float* w2fi = (const float*)d_in[9];
  const float* b2   = (const float*)d_in[10];
  const float* a2w1 = (const float*)d_in[11];
  const float* a2b1 = (const float*)d_in[12];
  const float* a2w2 = (const float*)d_in[13];
  const float* a2b2 = (const float*)d_in[14];
  float* outf = (float*)d_out;

  // xt (67MB bf16) parked in d_out: read only by conv1; conv2 overwrites d_out last.
  short* xt = (short*)d_out;

  char* wsb = (char*)d_ws;
  short* y1t  = (short*)wsb;                                   // 134,217,728 B
  short* wdt  = (short*)(wsb + 134217728);                     //  18,874,368 B
  float* gap1 = (float*)(wsb + 134217728 + 18874368);          //       8,192 B (B*CIN)
  float* gap2 = (float*)(wsb + 134217728 + 18874368 + 8192);   //      16,384 B (B*COUT)
  float* attn = (float*)(wsb + 134217728 + 18874368 + 8192 + 16384); // 256 B

  const float gsc = 1.f / (float)HW;

  // zero both GAP accumulators (atomically accumulated by fused kernels)
  hipMemsetAsync(gap1, 0, (size_t)B * (CIN + COUT) * sizeof(float), stream);

  // ---- layer 1 ----
  transpose_bf16_kernel<<<dim3(HW / 64, CIN / 32, B), 256, 0, stream>>>(x, xt, CIN, gap1);
  fd_attn_kernel<<<B, 64, 0, stream>>>(gap1, CIN, CIN / 4, gsc, a1w1, a1b1, a1w2, a1b2, attn);
  fd_synth_t_kernel<<<(B * CIN * COUT) / 256, 256, 0, stream>>>(w1fr, w1fi, attn, wdt, B, COUT, CIN);
  conv_mfma_kernel<128, 0><<<dim3(64, 2, 16), 512, 0, stream>>>(xt, wdt, b1, y1t, nullptr, gap2);

  // ---- layer 2 ----
  fd_attn_kernel<<<B, 64, 0, stream>>>(gap2, COUT, COUT / 4, gsc, a2w1, a2b1, a2w2, a2b2, attn);
  fd_synth_t_kernel<<<(B * COUT * COUT) / 256, 256, 0, stream>>>(w2fr, w2fi, attn, wdt, B, COUT, COUT);
  conv_mfma_kernel<256, 1><<<dim3(64, 2, 16), 512, 0, stream>>>(y1t, wdt, b2, nullptr, outf, nullptr);
}

// Round 4
// 1041.791 us; speedup vs baseline: 1.3593x; 1.3348x over previous
//
#include <hip/hip_runtime.h>
#include <hip/hip_bf16.h>
#include <math.h>

// ConvBlockFD R6 = R3 (verified 1099us) + conv double-buffer single-barrier prefetch.
// - Conv K-loop: 2-phase pipeline. Per kc: issue global loads for kc+1 (regs),
//   compute from LDS buf[cur] (144 MFMA hides load latency), vmcnt-drain + ds_write
//   to buf[cur^1], ONE barrier. (was: barrier, stage, barrier, compute).
// - Conv blocks 512 threads (8 waves: wc co-half x wy row-group) so prefetch is
//   3 short8/thread; LDS 2x25920B = 51.8KB (3 blocks/CU, not the limiter).
// - All aux kernels identical to the 1099us R3 run: separate fd_gap / gap_t_part /
//   gap_t_reduce, no atomics, ci-fastest synth, R3 conv epilogues (MODE0 scalar
//   2B contiguous-32B stores; MODE1 fp32 NCHW).

#define K_NUM 4
typedef __attribute__((ext_vector_type(8))) short short8;   // 8 bf16 = 4 VGPR
typedef __attribute__((ext_vector_type(4))) float f32x4;    // MFMA C/D frag

__device__ inline float bf2f(short s) {
  unsigned u = ((unsigned)(unsigned short)s) << 16;
  return __uint_as_float(u);
}
__device__ inline short f2bf(float f) {
  __hip_bfloat16 h = __float2bfloat16(f);
  return (short)*reinterpret_cast<unsigned short*>(&h);
}

// ---------------- GAP over fp32 NCHW (layer 1) ----------------
__global__ void fd_gap_kernel(const float* __restrict__ x, float* __restrict__ out, int HW) {
  const float4* p = (const float4*)(x + (size_t)blockIdx.x * HW);
  int n4 = HW >> 2;
  float s = 0.f;
  for (int i = threadIdx.x; i < n4; i += blockDim.x) {
    float4 v = p[i];
    s += v.x + v.y + v.z + v.w;
  }
  for (int off = 32; off > 0; off >>= 1) s += __shfl_down(s, off, 64);
  __shared__ float wsum[4];
  int lane = threadIdx.x & 63, w = threadIdx.x >> 6;
  if (lane == 0) wsum[w] = s;
  __syncthreads();
  if (threadIdx.x == 0) {
    float t = 0.f;
    int nw = blockDim.x >> 6;
    for (int i = 0; i < nw; ++i) t += wsum[i];
    out[blockIdx.x] = t / (float)HW;
  }
}

// ---------------- GAP over bf16 channels-last (layer 2) ----------------
__global__ __launch_bounds__(1024) void gap_t_part_kernel(
    const short* __restrict__ y, float* __restrict__ part) {
  const int HW = 16384, CO = 256;
  int b = blockIdx.y, ch = blockIdx.x;             // 16 chunks x 1024 px
  int t = threadIdx.x;
  int tg = t & 31, pg = t >> 5;
  const short* base = y + ((size_t)b * HW + (size_t)ch * 1024) * CO + tg * 8;
  float s[8];
#pragma unroll
  for (int j = 0; j < 8; ++j) s[j] = 0.f;
  for (int px = pg; px < 1024; px += 32) {
    short8 v = *(const short8*)(base + (size_t)px * CO);
#pragma unroll
    for (int j = 0; j < 8; ++j) s[j] += bf2f(v[j]);
  }
  __shared__ float red[32][32][8];  // 32 KB
#pragma unroll
  for (int j = 0; j < 8; ++j) red[pg][tg][j] = s[j];
  __syncthreads();
  if (t < 256) {
    float tot = 0.f;
    const float* r = (const float*)red;
#pragma unroll
    for (int p = 0; p < 32; ++p) tot += r[p * 256 + t];
    part[((size_t)b * 16 + ch) * 256 + t] = tot;
  }
}
__global__ void gap_t_reduce_kernel(const float* __restrict__ part, float* __restrict__ gap) {
  int b = blockIdx.x, co = threadIdx.x;
  float s = 0.f;
  for (int c = 0; c < 16; ++c) s += part[(b * 16 + c) * 256 + co];
  gap[b * 256 + co] = s * (1.f / 16384.f);
}

// ---------------- attention MLP + softmax ----------------
__global__ void fd_attn_kernel(const float* __restrict__ gap, int C, int Hd,
                               const float* __restrict__ w1, const float* __restrict__ b1,
                               const float* __restrict__ w2, const float* __restrict__ b2,
                               float* __restrict__ attn) {
  int b = blockIdx.x, j = threadIdx.x;
  __shared__ float h[64];
  __shared__ float z[K_NUM];
  if (j < Hd) {
    float s = b1[j];
    const float* g = gap + (size_t)b * C;
    for (int c = 0; c < C; ++c) s = fmaf(g[c], w1[c * Hd + j], s);
    h[j] = fmaxf(s, 0.f);
  }
  __syncthreads();
  if (j < K_NUM) {
    float s = b2[j];
    for (int c = 0; c < Hd; ++c) s = fmaf(h[c], w2[c * K_NUM + j], s);
    z[j] = s;
  }
  __syncthreads();
  if (j == 0) {
    float m = z[0];
    for (int k = 1; k < K_NUM; ++k) m = fmaxf(m, z[k]);
    float e[K_NUM], sum = 0.f;
    for (int k = 0; k < K_NUM; ++k) { e[k] = expf(z[k] - m); sum += e[k]; }
    for (int k = 0; k < K_NUM; ++k) attn[b * K_NUM + k] = e[k] / sum;
  }
}

// ---------------- synthesis: irfft2 + attention mix -> wd_t[b][9][ci/8][co][8] bf16 ----
__global__ void fd_synth_t_kernel(const float* __restrict__ wfr, const float* __restrict__ wfi,
                                  const float* __restrict__ attn, short* __restrict__ wdt,
                                  int B, int CO, int CI) {
  size_t gid = (size_t)blockIdx.x * blockDim.x + threadIdx.x;
  size_t total = (size_t)B * CI * CO;
  if (gid >= total) return;
  int ci = (int)(gid % CI);
  size_t t = gid / CI;
  int co = (int)(t % CO);
  int b = (int)(t / CO);

  float a[K_NUM];
  for (int k = 0; k < K_NUM; ++k) a[k] = attn[b * K_NUM + k];

  float Fr[3][2], Fi[3][2];
  for (int u = 0; u < 3; ++u) for (int v = 0; v < 2; ++v) { Fr[u][v] = 0.f; Fi[u][v] = 0.f; }
  for (int k = 0; k < K_NUM; ++k) {
    size_t base = ((((size_t)k * CO + co) * CI + ci) * 3) * 2;
    const float* pr = wfr + base;
    const float* pi = wfi + base;
    float ak = a[k];
    for (int u = 0; u < 3; ++u)
      for (int v = 0; v < 2; ++v) {
        Fr[u][v] = fmaf(ak, pr[u * 2 + v], Fr[u][v]);
        Fi[u][v] = fmaf(ak, pi[u * 2 + v], Fi[u][v]);
      }
  }

  const float CS[3] = {1.f, -0.5f, -0.5f};
  const float SN[3] = {0.f, 0.8660254037844386f, -0.8660254037844386f};
  float outv[9];
  for (int ai = 0; ai < 3; ++ai) {
    float Gr[2], Gi[2];
    for (int v = 0; v < 2; ++v) {
      float gr = 0.f, gi = 0.f;
      for (int u = 0; u < 3; ++u) {
        int idx = (u * ai) % 3;
        gr += Fr[u][v] * CS[idx] - Fi[u][v] * SN[idx];
        gi += Fr[u][v] * SN[idx] + Fi[u][v] * CS[idx];
      }
      Gr[v] = gr * (1.f / 3.f);
      Gi[v] = gi * (1.f / 3.f);
    }
    for (int bi = 0; bi < 3; ++bi)
      outv[ai * 3 + bi] = (Gr[0] + 2.f * (Gr[1] * CS[bi] - Gi[1] * SN[bi])) * (1.f / 3.f);
  }
  int ci8 = ci >> 3, cil = ci & 7;
  for (int s = 0; s < 9; ++s)
    wdt[((((size_t)b * 9 + s) * (CI / 8) + ci8) * CO + co) * 8 + cil] = f2bf(outv[s]);
}

// ---------------- transpose fp32 NCHW -> bf16 channels-last ----------------
__global__ __launch_bounds__(256) void transpose_bf16_kernel(
    const float* __restrict__ in, short* __restrict__ out, int C) {
  const int HW = 16384;
  __shared__ short t[64 * 40];
  int tid = threadIdx.x;
  int px0 = blockIdx.x * 64, c0 = blockIdx.y * 32, b = blockIdx.z;
  int px = tid & 63, cb = tid >> 6;
#pragma unroll
  for (int i = 0; i < 8; ++i) {
    int c = i * 4 + cb;
    float v = in[((size_t)b * C + c0 + c) * HW + px0 + px];
    t[px * 40 + c] = f2bf(v);
  }
  __syncthreads();
  int px2 = tid >> 2, g = tid & 3;
  short8 v = *(const short8*)(t + px2 * 40 + g * 8);
  *(short8*)(out + ((size_t)b * HW + px0 + px2) * C + c0 + g * 8) = v;
}

// ---------------- MFMA conv: 9 shift-GEMMs, 16x16x32 bf16, 2-phase dbuf ----------
// Block: 512 threads = 8 waves (wc = wave>>2 co-half, wy = wave&3 row group).
// Block tile: 128 co x 256 px; per wave 64 co x 64 px (4x4 frags).
// K-loop: single barrier per kc; global loads for kc+1 issued before compute.
// MODE 0 (conv1): mfma(xf,wf) -> D[px][co], scalar bf16 channels-last stores
//   (16 lanes contiguous 32B). MODE 1 (conv2): mfma(wf,xf) -> D[co][px], fp32 NCHW.
template <int CI, int MODE>
__global__ __launch_bounds__(512) void conv_mfma_kernel(
    const short* __restrict__ xin,   // [B][HW][CI] bf16
    const short* __restrict__ wdt,   // [B][9][CI/8][256][8] bf16
    const float* __restrict__ bias,  // [256]
    short* __restrict__ yout_t,      // MODE0 out
    float* __restrict__ yout_f) {    // MODE1 out
  const int H = 128, W = 128, HW = H * W, CO = 256;
  const int NKC = CI / 32;
  __shared__ short xs[2][18 * 18 * 40];  // 2 x 25920 B

  const int tid = threadIdx.x;
  const int w = tid >> 6;
  const int wy = w & 3, wc = w >> 2;
  const int lane = tid & 63;
  const int l15 = lane & 15, l4 = lane >> 4;
  const int tx0 = (blockIdx.x & 7) * 16, ty0 = (blockIdx.x >> 3) * 16;
  const int cob = blockIdx.y * 128 + wc * 64;
  const int b = blockIdx.z;

  // precompute this thread's staging coords (3 chunks; chunk 2 only if tid < 272)
  int sr[3], sc[3], sg[3];
#pragma unroll
  for (int i = 0; i < 3; ++i) {
    int idx = i * 512 + tid;
    int pxi = idx >> 2;
    sg[i] = idx & 3;
    sr[i] = pxi / 18;
    sc[i] = pxi - sr[i] * 18;
  }
  const bool has2 = (tid < 272);

  short8 pre[3];
  auto stage_load = [&](int kc) {
#pragma unroll
    for (int i = 0; i < 3; ++i) {
      if (i < 2 || has2) {
        int gy = ty0 + sr[i] - 1, gx = tx0 + sc[i] - 1;
        short8 v = {0, 0, 0, 0, 0, 0, 0, 0};
        if ((unsigned)gy < (unsigned)H && (unsigned)gx < (unsigned)W)
          v = *(const short8*)(xin + ((size_t)b * HW + gy * W + gx) * CI + kc * 32 + sg[i] * 8);
        pre[i] = v;
      }
    }
  };
  auto stage_write = [&](short* buf) {
#pragma unroll
    for (int i = 0; i < 3; ++i) {
      if (i < 2 || has2) {
        int pxi = sr[i] * 18 + sc[i];
        *(short8*)(buf + pxi * 40 + sg[i] * 8) = pre[i];
      }
    }
  };

  f32x4 acc[4][4];
#pragma unroll
  for (int i = 0; i < 4; ++i)
#pragma unroll
    for (int j = 0; j < 4; ++j)
      acc[i][j] = (f32x4){0.f, 0.f, 0.f, 0.f};

  // prologue: fill buf 0
  stage_load(0);
  stage_write(xs[0]);
  __syncthreads();

  int cur = 0;
  for (int kc = 0; kc < NKC; ++kc) {
    const bool more = (kc + 1 < NKC);
    if (more) stage_load(kc + 1);        // issue early; latency hides under MFMA
    const short* bufc = xs[cur];

#pragma unroll
    for (int dc = 0; dc < 3; ++dc) {
      short8 xf[6];
#pragma unroll
      for (int rr = 0; rr < 6; ++rr)
        xf[rr] = *(const short8*)(bufc + ((4 * wy + rr) * 18 + l15 + dc) * 40 + l4 * 8);
      short8 wf[3][4];
#pragma unroll
      for (int dr = 0; dr < 3; ++dr) {
        const short* wp = wdt + ((((size_t)b * 9 + dr * 3 + dc) * (CI / 8) + kc * 4 + l4) * CO + cob + l15) * 8;
#pragma unroll
        for (int cf = 0; cf < 4; ++cf)
          wf[dr][cf] = *(const short8*)(wp + cf * 128);
      }
#pragma unroll
      for (int dr = 0; dr < 3; ++dr)
#pragma unroll
        for (int nf = 0; nf < 4; ++nf)
#pragma unroll
          for (int cf = 0; cf < 4; ++cf) {
            if (MODE == 0)
              acc[nf][cf] = __builtin_amdgcn_mfma_f32_16x16x32_bf16(
                  xf[nf + dr], wf[dr][cf], acc[nf][cf], 0, 0, 0);
            else
              acc[nf][cf] = __builtin_amdgcn_mfma_f32_16x16x32_bf16(
                  wf[dr][cf], xf[nf + dr], acc[nf][cf], 0, 0, 0);
          }
    }

    if (more) stage_write(xs[cur ^ 1]);  // compiler inserts vmcnt wait on pre[]
    __syncthreads();                     // one barrier per kc
    cur ^= 1;
  }

  if (MODE == 0) {
    // D[m=px-col][n=co]: lane holds col = l4*4+r, co = l15 (16 lanes = 32B contig)
#pragma unroll
    for (int cf = 0; cf < 4; ++cf) {
      float bs = bias[cob + cf * 16 + l15];
#pragma unroll
      for (int nf = 0; nf < 4; ++nf) {
        int row = ty0 + 4 * wy + nf;
#pragma unroll
        for (int r = 0; r < 4; ++r) {
          int col = tx0 + l4 * 4 + r;
          float v = fmaxf(acc[nf][cf][r] + bs, 0.f);
          yout_t[((size_t)b * HW + (size_t)row * W + col) * CO + cob + cf * 16 + l15] = f2bf(v);
        }
      }
    }
  } else {
    // D[m=co][n=px-col]: lane holds co = cf*16 + l4*4 + r, col = l15; fp32 NCHW
#pragma unroll
    for (int cf = 0; cf < 4; ++cf) {
#pragma unroll
      for (int r = 0; r < 4; ++r) {
        int co = cob + cf * 16 + l4 * 4 + r;
        float bs = bias[co];
#pragma unroll
        for (int nf = 0; nf < 4; ++nf) {
          int row = ty0 + 4 * wy + nf;
          int col = tx0 + l15;
          yout_f[((size_t)b * CO + co) * HW + (size_t)row * W + col] =
              fmaxf(acc[nf][cf][r] + bs, 0.f);
        }
      }
    }
  }
}

extern "C" void kernel_launch(void* const* d_in, const int* in_sizes, int n_in,
                              void* d_out, int out_size, void* d_ws, size_t ws_size,
                              hipStream_t stream) {
  const int B = 16, CIN = 128, COUT = 256, H = 128, W = 128, HW = H * W;

  const float* x    = (const float*)d_in[0];
  const float* w1fr = (const float*)d_in[1];
  const float* w1fi = (const float*)d_in[2];
  const float* b1   = (const float*)d_in[3];
  const float* a1w1 = (const float*)d_in[4];
  const float* a1b1 = (const float*)d_in[5];
  const float* a1w2 = (const float*)d_in[6];
  const float* a1b2 = (const float*)d_in[7];
  const float* w2fr = (const float*)d_in[8];
  const float* w2fi = (const float*)d_in[9];
  const float* b2   = (const float*)d_in[10];
  const float* a2w1 = (const float*)d_in[11];
  const float* a2b1 = (const float*)d_in[12];
  const float* a2w2 = (const float*)d_in[13];
  const float* a2b2 = (const float*)d_in[14];
  float* outf = (float*)d_out;

  // xt (67MB bf16) parked in d_out: read only by conv1; conv2 overwrites d_out last.
  short* xt = (short*)d_out;

  char* wsb = (char*)d_ws;
  short* y1t  = (short*)wsb;                                   // 134,217,728 B
  short* wdt  = (short*)(wsb + 134217728);                     //  18,874,368 B
  float* gprt = (float*)(wsb + 134217728 + 18874368);          //     262,144 B
  float* gap  = (float*)(wsb + 134217728 + 18874368 + 262144); //      16,384 B
  float* attn = (float*)(wsb + 134217728 + 18874368 + 262144 + 16384); // 256 B

  // ---- layer 1 ----
  transpose_bf16_kernel<<<dim3(HW / 64, CIN / 32, B), 256, 0, stream>>>(x, xt, CIN);
  fd_gap_kernel<<<B * CIN, 256, 0, stream>>>(x, gap, HW);
  fd_attn_kernel<<<B, 64, 0, stream>>>(gap, CIN, CIN / 4, a1w1, a1b1, a1w2, a1b2, attn);
  fd_synth_t_kernel<<<(B * CIN * COUT) / 256, 256, 0, stream>>>(w1fr, w1fi, attn, wdt, B, COUT, CIN);
  conv_mfma_kernel<128, 0><<<dim3(64, 2, 16), 512, 0, stream>>>(xt, wdt, b1, y1t, nullptr);

  // ---- layer 2 ----
  gap_t_part_kernel<<<dim3(16, B), 1024, 0, stream>>>(y1t, gprt);
  gap_t_reduce_kernel<<<B, 256, 0, stream>>>(gprt, gap);
  fd_attn_kernel<<<B, 64, 0, stream>>>(gap, COUT, COUT / 4, a2w1, a2b1, a2w2, a2b2, attn);
  fd_synth_t_kernel<<<(B * COUT * COUT) / 256, 256, 0, stream>>>(w2fr, w2fi, attn, wdt, B, COUT, COUT);
  conv_mfma_kernel<256, 1><<<dim3(64, 2, 16), 512, 0, stream>>>(y1t, wdt, b2, nullptr, outf);
}

// Round 5
// 1007.488 us; speedup vs baseline: 1.4056x; 1.0340x over previous
//
#include <hip/hip_runtime.h>
#include <hip/hip_bf16.h>
#include <math.h>

// ConvBlockFD R7 = R6 (verified 1042us) + atomic-free GAP fusion.
// - Layer-1 GAP fused into transpose: per-wave channel partials -> gpart1 (d_out
//   scratch), tiny gap_reduce kernel. Removes fd_gap's 134MB re-read of x.
// - Layer-2 GAP fused into conv1 (MODE0) epilogue: per-wave co partials over its
//   64px -> gpart2, same reduce kernel. Removes gap_t_part's 134MB re-read of y1t.
// - NO atomics (R4/R5 post-mortem: 1M device-scope atomicAdds onto 4-16KB was the
//   probable ~300us regression; partials + reduce instead).
// - Conv kernels: R6's 2-phase single-barrier dbuf (conv2 340us, MfmaUtil 40%).
// d_out layout: [0,67MB) xt bf16 (dead before conv2 writes), [67,69.2MB) gpart1,
// [69.2,73.4MB) gpart2 (both dead before conv2 writes).

#define K_NUM 4
typedef __attribute__((ext_vector_type(8))) short short8;   // 8 bf16 = 4 VGPR
typedef __attribute__((ext_vector_type(4))) float f32x4;    // MFMA C/D frag

__device__ inline float bf2f(short s) {
  unsigned u = ((unsigned)(unsigned short)s) << 16;
  return __uint_as_float(u);
}
__device__ inline short f2bf(float f) {
  __hip_bfloat16 h = __float2bfloat16(f);
  return (short)*reinterpret_cast<unsigned short*>(&h);
}

// ---------------- partial-sum reduce: gap[row] = scale * sum(part[row][0..255]) ----
// One wave per row; lane loads float4 (1KB contiguous per wave).
__global__ __launch_bounds__(256) void gap_reduce_kernel(
    const float* __restrict__ part, float* __restrict__ gap, float scale) {
  int row = blockIdx.x * 4 + (threadIdx.x >> 6);
  int lane = threadIdx.x & 63;
  float4 v = *(const float4*)(part + (size_t)row * 256 + lane * 4);
  float s = v.x + v.y + v.z + v.w;
#pragma unroll
  for (int m = 1; m <= 32; m <<= 1) s += __shfl_xor(s, m, 64);
  if (lane == 0) gap[row] = s * scale;
}

// ---------------- attention MLP + softmax ----------------
__global__ void fd_attn_kernel(const float* __restrict__ gap, int C, int Hd,
                               const float* __restrict__ w1, const float* __restrict__ b1,
                               const float* __restrict__ w2, const float* __restrict__ b2,
                               float* __restrict__ attn) {
  int b = blockIdx.x, j = threadIdx.x;
  __shared__ float h[64];
  __shared__ float z[K_NUM];
  if (j < Hd) {
    float s = b1[j];
    const float* g = gap + (size_t)b * C;
    for (int c = 0; c < C; ++c) s = fmaf(g[c], w1[c * Hd + j], s);
    h[j] = fmaxf(s, 0.f);
  }
  __syncthreads();
  if (j < K_NUM) {
    float s = b2[j];
    for (int c = 0; c < Hd; ++c) s = fmaf(h[c], w2[c * K_NUM + j], s);
    z[j] = s;
  }
  __syncthreads();
  if (j == 0) {
    float m = z[0];
    for (int k = 1; k < K_NUM; ++k) m = fmaxf(m, z[k]);
    float e[K_NUM], sum = 0.f;
    for (int k = 0; k < K_NUM; ++k) { e[k] = expf(z[k] - m); sum += e[k]; }
    for (int k = 0; k < K_NUM; ++k) attn[b * K_NUM + k] = e[k] / sum;
  }
}

// ---------------- synthesis: irfft2 + attention mix -> wd_t[b][9][ci/8][co][8] bf16 ----
__global__ void fd_synth_t_kernel(const float* __restrict__ wfr, const float* __restrict__ wfi,
                                  const float* __restrict__ attn, short* __restrict__ wdt,
                                  int B, int CO, int CI) {
  size_t gid = (size_t)blockIdx.x * blockDim.x + threadIdx.x;
  size_t total = (size_t)B * CI * CO;
  if (gid >= total) return;
  int ci = (int)(gid % CI);
  size_t t = gid / CI;
  int co = (int)(t % CO);
  int b = (int)(t / CO);

  float a[K_NUM];
  for (int k = 0; k < K_NUM; ++k) a[k] = attn[b * K_NUM + k];

  float Fr[3][2], Fi[3][2];
  for (int u = 0; u < 3; ++u) for (int v = 0; v < 2; ++v) { Fr[u][v] = 0.f; Fi[u][v] = 0.f; }
  for (int k = 0; k < K_NUM; ++k) {
    size_t base = ((((size_t)k * CO + co) * CI + ci) * 3) * 2;
    const float* pr = wfr + base;
    const float* pi = wfi + base;
    float ak = a[k];
    for (int u = 0; u < 3; ++u)
      for (int v = 0; v < 2; ++v) {
        Fr[u][v] = fmaf(ak, pr[u * 2 + v], Fr[u][v]);
        Fi[u][v] = fmaf(ak, pi[u * 2 + v], Fi[u][v]);
      }
  }

  const float CS[3] = {1.f, -0.5f, -0.5f};
  const float SN[3] = {0.f, 0.8660254037844386f, -0.8660254037844386f};
  float outv[9];
  for (int ai = 0; ai < 3; ++ai) {
    float Gr[2], Gi[2];
    for (int v = 0; v < 2; ++v) {
      float gr = 0.f, gi = 0.f;
      for (int u = 0; u < 3; ++u) {
        int idx = (u * ai) % 3;
        gr += Fr[u][v] * CS[idx] - Fi[u][v] * SN[idx];
        gi += Fr[u][v] * SN[idx] + Fi[u][v] * CS[idx];
      }
      Gr[v] = gr * (1.f / 3.f);
      Gi[v] = gi * (1.f / 3.f);
    }
    for (int bi = 0; bi < 3; ++bi)
      outv[ai * 3 + bi] = (Gr[0] + 2.f * (Gr[1] * CS[bi] - Gi[1] * SN[bi])) * (1.f / 3.f);
  }
  int ci8 = ci >> 3, cil = ci & 7;
  for (int s = 0; s < 9; ++s)
    wdt[((((size_t)b * 9 + s) * (CI / 8) + ci8) * CO + co) * 8 + cil] = f2bf(outv[s]);
}

// ---------------- transpose fp32 NCHW -> bf16 channels-last + layer-1 GAP partials ----
__global__ __launch_bounds__(256) void transpose_bf16_kernel(
    const float* __restrict__ in, short* __restrict__ out, int C,
    float* __restrict__ gpart1) {   // [B*C][256] per-pxblock partials
  const int HW = 16384;
  __shared__ short t[64 * 40];
  int tid = threadIdx.x;
  int px0 = blockIdx.x * 64, c0 = blockIdx.y * 32, b = blockIdx.z;
  int px = tid & 63, cb = tid >> 6;   // wave cb handles c = {cb, 4+cb, ..., 28+cb}
  float sums[8];
#pragma unroll
  for (int i = 0; i < 8; ++i) {
    int c = i * 4 + cb;
    float v = in[((size_t)b * C + c0 + c) * HW + px0 + px];
    t[px * 40 + c] = f2bf(v);
    sums[i] = v;
  }
  __syncthreads();
  int px2 = tid >> 2, g = tid & 3;
  short8 v = *(const short8*)(t + px2 * 40 + g * 8);
  *(short8*)(out + ((size_t)b * HW + px0 + px2) * C + c0 + g * 8) = v;
  // per-wave channel partials over 64 px (no atomics)
#pragma unroll
  for (int m = 1; m <= 32; m <<= 1)
#pragma unroll
    for (int i = 0; i < 8; ++i) sums[i] += __shfl_xor(sums[i], m, 64);
  if ((tid & 63) == 0)
#pragma unroll
    for (int i = 0; i < 8; ++i)
      gpart1[((size_t)b * C + c0 + i * 4 + cb) * 256 + blockIdx.x] = sums[i];
}

// ---------------- MFMA conv: 9 shift-GEMMs, 16x16x32 bf16, 2-phase dbuf ----------
// Block: 512 threads = 8 waves (wc = wave>>2 co-half, wy = wave&3 row group).
// Block tile: 128 co x 256 px; per wave 64 co x 64 px (4x4 frags).
// K-loop: single barrier per kc; global loads for kc+1 issued before compute.
// MODE 0 (conv1): mfma(xf,wf) -> D[px][co], bf16 channels-last stores + per-wave
//   GAP partials -> gpart2[b][co][256] (slot = bx*4+wy). MODE 1 (conv2): fp32 NCHW.
template <int CI, int MODE>
__global__ __launch_bounds__(512) void conv_mfma_kernel(
    const short* __restrict__ xin,   // [B][HW][CI] bf16
    const short* __restrict__ wdt,   // [B][9][CI/8][256][8] bf16
    const float* __restrict__ bias,  // [256]
    short* __restrict__ yout_t,      // MODE0 out
    float* __restrict__ yout_f,      // MODE1 out
    float* __restrict__ gpart2) {    // MODE0: [B*256][256] GAP partials
  const int H = 128, W = 128, HW = H * W, CO = 256;
  const int NKC = CI / 32;
  __shared__ short xs[2][18 * 18 * 40];  // 2 x 25920 B

  const int tid = threadIdx.x;
  const int w = tid >> 6;
  const int wy = w & 3, wc = w >> 2;
  const int lane = tid & 63;
  const int l15 = lane & 15, l4 = lane >> 4;
  const int tx0 = (blockIdx.x & 7) * 16, ty0 = (blockIdx.x >> 3) * 16;
  const int cob = blockIdx.y * 128 + wc * 64;
  const int b = blockIdx.z;

  // precompute this thread's staging coords (3 chunks; chunk 2 only if tid < 272)
  int sr[3], sc[3], sg[3];
#pragma unroll
  for (int i = 0; i < 3; ++i) {
    int idx = i * 512 + tid;
    int pxi = idx >> 2;
    sg[i] = idx & 3;
    sr[i] = pxi / 18;
    sc[i] = pxi - sr[i] * 18;
  }
  const bool has2 = (tid < 272);

  short8 pre[3];
  auto stage_load = [&](int kc) {
#pragma unroll
    for (int i = 0; i < 3; ++i) {
      if (i < 2 || has2) {
        int gy = ty0 + sr[i] - 1, gx = tx0 + sc[i] - 1;
        short8 v = {0, 0, 0, 0, 0, 0, 0, 0};
        if ((unsigned)gy < (unsigned)H && (unsigned)gx < (unsigned)W)
          v = *(const short8*)(xin + ((size_t)b * HW + gy * W + gx) * CI + kc * 32 + sg[i] * 8);
        pre[i] = v;
      }
    }
  };
  auto stage_write = [&](short* buf) {
#pragma unroll
    for (int i = 0; i < 3; ++i) {
      if (i < 2 || has2) {
        int pxi = sr[i] * 18 + sc[i];
        *(short8*)(buf + pxi * 40 + sg[i] * 8) = pre[i];
      }
    }
  };

  f32x4 acc[4][4];
#pragma unroll
  for (int i = 0; i < 4; ++i)
#pragma unroll
    for (int j = 0; j < 4; ++j)
      acc[i][j] = (f32x4){0.f, 0.f, 0.f, 0.f};

  // prologue: fill buf 0
  stage_load(0);
  stage_write(xs[0]);
  __syncthreads();

  int cur = 0;
  for (int kc = 0; kc < NKC; ++kc) {
    const bool more = (kc + 1 < NKC);
    if (more) stage_load(kc + 1);        // issue early; latency hides under MFMA
    const short* bufc = xs[cur];

#pragma unroll
    for (int dc = 0; dc < 3; ++dc) {
      short8 xf[6];
#pragma unroll
      for (int rr = 0; rr < 6; ++rr)
        xf[rr] = *(const short8*)(bufc + ((4 * wy + rr) * 18 + l15 + dc) * 40 + l4 * 8);
      short8 wf[3][4];
#pragma unroll
      for (int dr = 0; dr < 3; ++dr) {
        const short* wp = wdt + ((((size_t)b * 9 + dr * 3 + dc) * (CI / 8) + kc * 4 + l4) * CO + cob + l15) * 8;
#pragma unroll
        for (int cf = 0; cf < 4; ++cf)
          wf[dr][cf] = *(const short8*)(wp + cf * 128);
      }
#pragma unroll
      for (int dr = 0; dr < 3; ++dr)
#pragma unroll
        for (int nf = 0; nf < 4; ++nf)
#pragma unroll
          for (int cf = 0; cf < 4; ++cf) {
            if (MODE == 0)
              acc[nf][cf] = __builtin_amdgcn_mfma_f32_16x16x32_bf16(
                  xf[nf + dr], wf[dr][cf], acc[nf][cf], 0, 0, 0);
            else
              acc[nf][cf] = __builtin_amdgcn_mfma_f32_16x16x32_bf16(
                  wf[dr][cf], xf[nf + dr], acc[nf][cf], 0, 0, 0);
          }
    }

    if (more) stage_write(xs[cur ^ 1]);  // compiler inserts vmcnt wait on pre[]
    __syncthreads();                     // one barrier per kc
    cur ^= 1;
  }

  if (MODE == 0) {
    // D[m=px-col][n=co]: lane holds col = l4*4+r, co = l15 (16 lanes = 32B contig)
    float gs[4];
#pragma unroll
    for (int cf = 0; cf < 4; ++cf) gs[cf] = 0.f;
#pragma unroll
    for (int cf = 0; cf < 4; ++cf) {
      float bs = bias[cob + cf * 16 + l15];
#pragma unroll
      for (int nf = 0; nf < 4; ++nf) {
        int row = ty0 + 4 * wy + nf;
#pragma unroll
        for (int r = 0; r < 4; ++r) {
          int col = tx0 + l4 * 4 + r;
          float v = fmaxf(acc[nf][cf][r] + bs, 0.f);
          gs[cf] += v;
          yout_t[((size_t)b * HW + (size_t)row * W + col) * CO + cob + cf * 16 + l15] = f2bf(v);
        }
      }
    }
    // per-wave GAP partials: reduce over l4 (same co = cob+cf*16+l15), no atomics
#pragma unroll
    for (int cf = 0; cf < 4; ++cf) {
      gs[cf] += __shfl_xor(gs[cf], 16, 64);
      gs[cf] += __shfl_xor(gs[cf], 32, 64);
    }
    if (l4 == 0) {
      int pslot = blockIdx.x * 4 + wy;   // 64 px-blocks x 4 row-groups = 256 slots
#pragma unroll
      for (int cf = 0; cf < 4; ++cf)
        gpart2[((size_t)b * 256 + cob + cf * 16 + l15) * 256 + pslot] = gs[cf];
    }
  } else {
    // D[m=co][n=px-col]: lane holds co = cf*16 + l4*4 + r, col = l15; fp32 NCHW
#pragma unroll
    for (int cf = 0; cf < 4; ++cf) {
#pragma unroll
      for (int r = 0; r < 4; ++r) {
        int co = cob + cf * 16 + l4 * 4 + r;
        float bs = bias[co];
#pragma unroll
        for (int nf = 0; nf < 4; ++nf) {
          int row = ty0 + 4 * wy + nf;
          int col = tx0 + l15;
          yout_f[((size_t)b * CO + co) * HW + (size_t)row * W + col] =
              fmaxf(acc[nf][cf][r] + bs, 0.f);
        }
      }
    }
  }
}

extern "C" void kernel_launch(void* const* d_in, const int* in_sizes, int n_in,
                              void* d_out, int out_size, void* d_ws, size_t ws_size,
                              hipStream_t stream) {
  const int B = 16, CIN = 128, COUT = 256, H = 128, W = 128, HW = H * W;

  const float* x    = (const float*)d_in[0];
  const float* w1fr = (const float*)d_in[1];
  const float* w1fi = (const float*)d_in[2];
  const float* b1   = (const float*)d_in[3];
  const float* a1w1 = (const float*)d_in[4];
  const float* a1b1 = (const float*)d_in[5];
  const float* a1w2 = (const float*)d_in[6];
  const float* a1b2 = (const float*)d_in[7];
  const float* w2fr = (const float*)d_in[8];
  const float* w2fi = (const float*)d_in[9];
  const float* b2   = (const float*)d_in[10];
  const float* a2w1 = (const float*)d_in[11];
  const float* a2b1 = (const float*)d_in[12];
  const float* a2w2 = (const float*)d_in[13];
  const float* a2b2 = (const float*)d_in[14];
  float* outf = (float*)d_out;

  // d_out scratch (all dead before conv2 overwrites d_out):
  short* xt     = (short*)d_out;                              // 67,108,864 B
  float* gpart1 = (float*)((char*)d_out + 67108864);          //  2,097,152 B (B*CIN x 256)
  float* gpart2 = (float*)((char*)d_out + 69206016);          //  4,194,304 B (B*COUT x 256)

  char* wsb = (char*)d_ws;
  short* y1t  = (short*)wsb;                                   // 134,217,728 B
  short* wdt  = (short*)(wsb + 134217728);                     //  18,874,368 B
  float* gap1 = (float*)(wsb + 134217728 + 18874368);          //       8,192 B
  float* gap2 = (float*)(wsb + 134217728 + 18874368 + 8192);   //      16,384 B
  float* attn = (float*)(wsb + 134217728 + 18874368 + 8192 + 16384); // 256 B

  const float gsc = 1.f / (float)HW;

  // ---- layer 1 ----
  transpose_bf16_kernel<<<dim3(HW / 64, CIN / 32, B), 256, 0, stream>>>(x, xt, CIN, gpart1);
  gap_reduce_kernel<<<(B * CIN) / 4, 256, 0, stream>>>(gpart1, gap1, gsc);
  fd_attn_kernel<<<B, 64, 0, stream>>>(gap1, CIN, CIN / 4, a1w1, a1b1, a1w2, a1b2, attn);
  fd_synth_t_kernel<<<(B * CIN * COUT) / 256, 256, 0, stream>>>(w1fr, w1fi, attn, wdt, B, COUT, CIN);
  conv_mfma_kernel<128, 0><<<dim3(64, 2, 16), 512, 0, stream>>>(xt, wdt, b1, y1t, nullptr, gpart2);

  // ---- layer 2 ----
  gap_reduce_kernel<<<(B * COUT) / 4, 256, 0, stream>>>(gpart2, gap2, gsc);
  fd_attn_kernel<<<B, 64, 0, stream>>>(gap2, COUT, COUT / 4, a2w1, a2b1, a2w2, a2b2, attn);
  fd_synth_t_kernel<<<(B * COUT * COUT) / 256, 256, 0, stream>>>(w2fr, w2fi, attn, wdt, B, COUT, COUT);
  conv_mfma_kernel<256, 1><<<dim3(64, 2, 16), 512, 0, stream>>>(y1t, wdt, b2, nullptr, outf, nullptr);
}

// Round 6
// 925.605 us; speedup vs baseline: 1.5300x; 1.0885x over previous
//
#include <hip/hip_runtime.h>
#include <hip/hip_bf16.h>
#include <math.h>

// ConvBlockFD R8 = R7 (verified 1007us) + conv wave-shape change for wf L2 reuse.
// Theory: conv was bound by weight-fragment L2 traffic (4 wy-waves per cob load
// identical wf: 288KB/block-kc vs 73.7KB unique; ~5.1K cyc/CU vs 5.6K MFMA floor).
// Change: 8 waves = 4 co-blocks x 2 row-groups (was 2x4); block tile 256co x 256px;
// per-wave 64co x 128px (acc[8][4], xf[10]); wf per MFMA halves. wf[4] kept live
// only inside dr loop (VGPR ~216, __launch_bounds__(512,2)). Grid y=1 (1024 blocks).
// Aux kernels unchanged from R7 (atomic-free fused GAP, ci-fastest synth).

#define K_NUM 4
typedef __attribute__((ext_vector_type(8))) short short8;   // 8 bf16 = 4 VGPR
typedef __attribute__((ext_vector_type(4))) float f32x4;    // MFMA C/D frag

__device__ inline float bf2f(short s) {
  unsigned u = ((unsigned)(unsigned short)s) << 16;
  return __uint_as_float(u);
}
__device__ inline short f2bf(float f) {
  __hip_bfloat16 h = __float2bfloat16(f);
  return (short)*reinterpret_cast<unsigned short*>(&h);
}

// ---------------- partial-sum reduce: gap[row] = scale * sum(part[row][0..4*n4)) ----
__global__ __launch_bounds__(256) void gap_reduce_kernel(
    const float* __restrict__ part, float* __restrict__ gap, float scale, int n4) {
  int row = blockIdx.x * 4 + (threadIdx.x >> 6);
  int lane = threadIdx.x & 63;
  float4 v = {0.f, 0.f, 0.f, 0.f};
  if (lane < n4) v = *(const float4*)(part + (size_t)row * 256 + lane * 4);
  float s = v.x + v.y + v.z + v.w;
#pragma unroll
  for (int m = 1; m <= 32; m <<= 1) s += __shfl_xor(s, m, 64);
  if (lane == 0) gap[row] = s * scale;
}

// ---------------- attention MLP + softmax ----------------
__global__ void fd_attn_kernel(const float* __restrict__ gap, int C, int Hd,
                               const float* __restrict__ w1, const float* __restrict__ b1,
                               const float* __restrict__ w2, const float* __restrict__ b2,
                               float* __restrict__ attn) {
  int b = blockIdx.x, j = threadIdx.x;
  __shared__ float h[64];
  __shared__ float z[K_NUM];
  if (j < Hd) {
    float s = b1[j];
    const float* g = gap + (size_t)b * C;
    for (int c = 0; c < C; ++c) s = fmaf(g[c], w1[c * Hd + j], s);
    h[j] = fmaxf(s, 0.f);
  }
  __syncthreads();
  if (j < K_NUM) {
    float s = b2[j];
    for (int c = 0; c < Hd; ++c) s = fmaf(h[c], w2[c * K_NUM + j], s);
    z[j] = s;
  }
  __syncthreads();
  if (j == 0) {
    float m = z[0];
    for (int k = 1; k < K_NUM; ++k) m = fmaxf(m, z[k]);
    float e[K_NUM], sum = 0.f;
    for (int k = 0; k < K_NUM; ++k) { e[k] = expf(z[k] - m); sum += e[k]; }
    for (int k = 0; k < K_NUM; ++k) attn[b * K_NUM + k] = e[k] / sum;
  }
}

// ---------------- synthesis: irfft2 + attention mix -> wd_t[b][9][ci/8][co][8] bf16 ----
__global__ void fd_synth_t_kernel(const float* __restrict__ wfr, const float* __restrict__ wfi,
                                  const float* __restrict__ attn, short* __restrict__ wdt,
                                  int B, int CO, int CI) {
  size_t gid = (size_t)blockIdx.x * blockDim.x + threadIdx.x;
  size_t total = (size_t)B * CI * CO;
  if (gid >= total) return;
  int ci = (int)(gid % CI);
  size_t t = gid / CI;
  int co = (int)(t % CO);
  int b = (int)(t / CO);

  float a[K_NUM];
  for (int k = 0; k < K_NUM; ++k) a[k] = attn[b * K_NUM + k];

  float Fr[3][2], Fi[3][2];
  for (int u = 0; u < 3; ++u) for (int v = 0; v < 2; ++v) { Fr[u][v] = 0.f; Fi[u][v] = 0.f; }
  for (int k = 0; k < K_NUM; ++k) {
    size_t base = ((((size_t)k * CO + co) * CI + ci) * 3) * 2;
    const float* pr = wfr + base;
    const float* pi = wfi + base;
    float ak = a[k];
    for (int u = 0; u < 3; ++u)
      for (int v = 0; v < 2; ++v) {
        Fr[u][v] = fmaf(ak, pr[u * 2 + v], Fr[u][v]);
        Fi[u][v] = fmaf(ak, pi[u * 2 + v], Fi[u][v]);
      }
  }

  const float CS[3] = {1.f, -0.5f, -0.5f};
  const float SN[3] = {0.f, 0.8660254037844386f, -0.8660254037844386f};
  float outv[9];
  for (int ai = 0; ai < 3; ++ai) {
    float Gr[2], Gi[2];
    for (int v = 0; v < 2; ++v) {
      float gr = 0.f, gi = 0.f;
      for (int u = 0; u < 3; ++u) {
        int idx = (u * ai) % 3;
        gr += Fr[u][v] * CS[idx] - Fi[u][v] * SN[idx];
        gi += Fr[u][v] * SN[idx] + Fi[u][v] * CS[idx];
      }
      Gr[v] = gr * (1.f / 3.f);
      Gi[v] = gi * (1.f / 3.f);
    }
    for (int bi = 0; bi < 3; ++bi)
      outv[ai * 3 + bi] = (Gr[0] + 2.f * (Gr[1] * CS[bi] - Gi[1] * SN[bi])) * (1.f / 3.f);
  }
  int ci8 = ci >> 3, cil = ci & 7;
  for (int s = 0; s < 9; ++s)
    wdt[((((size_t)b * 9 + s) * (CI / 8) + ci8) * CO + co) * 8 + cil] = f2bf(outv[s]);
}

// ---------------- transpose fp32 NCHW -> bf16 channels-last + layer-1 GAP partials ----
__global__ __launch_bounds__(256) void transpose_bf16_kernel(
    const float* __restrict__ in, short* __restrict__ out, int C,
    float* __restrict__ gpart1) {   // [B*C][256] per-pxblock partials
  const int HW = 16384;
  __shared__ short t[64 * 40];
  int tid = threadIdx.x;
  int px0 = blockIdx.x * 64, c0 = blockIdx.y * 32, b = blockIdx.z;
  int px = tid & 63, cb = tid >> 6;   // wave cb handles c = {cb, 4+cb, ..., 28+cb}
  float sums[8];
#pragma unroll
  for (int i = 0; i < 8; ++i) {
    int c = i * 4 + cb;
    float v = in[((size_t)b * C + c0 + c) * HW + px0 + px];
    t[px * 40 + c] = f2bf(v);
    sums[i] = v;
  }
  __syncthreads();
  int px2 = tid >> 2, g = tid & 3;
  short8 v = *(const short8*)(t + px2 * 40 + g * 8);
  *(short8*)(out + ((size_t)b * HW + px0 + px2) * C + c0 + g * 8) = v;
  // per-wave channel partials over 64 px (no atomics)
#pragma unroll
  for (int m = 1; m <= 32; m <<= 1)
#pragma unroll
    for (int i = 0; i < 8; ++i) sums[i] += __shfl_xor(sums[i], m, 64);
  if ((tid & 63) == 0)
#pragma unroll
    for (int i = 0; i < 8; ++i)
      gpart1[((size_t)b * C + c0 + i * 4 + cb) * 256 + blockIdx.x] = sums[i];
}

// ---------------- MFMA conv: 9 shift-GEMMs, 16x16x32 bf16, 2-phase dbuf ----------
// Block: 512 threads = 8 waves: wc = w>>1 (4 co-blocks of 64), wy = w&1 (2 row groups).
// Block tile: 256 co x 256 px (16x16 spatial); per wave 64 co x 128 px (8 rows).
// acc[8][4]; xf[10] rows per dc; wf[4] live per (dc,dr) only.
// K-loop: single barrier per kc; global loads for kc+1 issued before compute.
// MODE 0 (conv1): mfma(xf,wf) -> D[px][co], bf16 channels-last + GAP partials
//   (pslot = bx*2+wy, 128 slots). MODE 1 (conv2): mfma(wf,xf) -> D[co][px], fp32 NCHW.
template <int CI, int MODE>
__global__ __launch_bounds__(512, 2) void conv_mfma_kernel(
    const short* __restrict__ xin,   // [B][HW][CI] bf16
    const short* __restrict__ wdt,   // [B][9][CI/8][256][8] bf16
    const float* __restrict__ bias,  // [256]
    short* __restrict__ yout_t,      // MODE0 out
    float* __restrict__ yout_f,      // MODE1 out
    float* __restrict__ gpart2) {    // MODE0: [B*256][256] GAP partials (128 used)
  const int H = 128, W = 128, HW = H * W, CO = 256;
  const int NKC = CI / 32;
  __shared__ short xs[2][18 * 18 * 40];  // 2 x 25920 B

  const int tid = threadIdx.x;
  const int w = tid >> 6;
  const int wy = w & 1, wc = w >> 1;
  const int lane = tid & 63;
  const int l15 = lane & 15, l4 = lane >> 4;
  const int tx0 = (blockIdx.x & 7) * 16, ty0 = (blockIdx.x >> 3) * 16;
  const int cob = wc * 64;
  const int b = blockIdx.z;

  // staging coords (3 chunks; chunk 2 only if tid < 272)
  int sr[3], sc[3], sg[3];
#pragma unroll
  for (int i = 0; i < 3; ++i) {
    int idx = i * 512 + tid;
    int pxi = idx >> 2;
    sg[i] = idx & 3;
    sr[i] = pxi / 18;
    sc[i] = pxi - sr[i] * 18;
  }
  const bool has2 = (tid < 272);

  short8 pre[3];
  auto stage_load = [&](int kc) {
#pragma unroll
    for (int i = 0; i < 3; ++i) {
      if (i < 2 || has2) {
        int gy = ty0 + sr[i] - 1, gx = tx0 + sc[i] - 1;
        short8 v = {0, 0, 0, 0, 0, 0, 0, 0};
        if ((unsigned)gy < (unsigned)H && (unsigned)gx < (unsigned)W)
          v = *(const short8*)(xin + ((size_t)b * HW + gy * W + gx) * CI + kc * 32 + sg[i] * 8);
        pre[i] = v;
      }
    }
  };
  auto stage_write = [&](short* buf) {
#pragma unroll
    for (int i = 0; i < 3; ++i) {
      if (i < 2 || has2) {
        int pxi = sr[i] * 18 + sc[i];
        *(short8*)(buf + pxi * 40 + sg[i] * 8) = pre[i];
      }
    }
  };

  f32x4 acc[8][4];
#pragma unroll
  for (int i = 0; i < 8; ++i)
#pragma unroll
    for (int j = 0; j < 4; ++j)
      acc[i][j] = (f32x4){0.f, 0.f, 0.f, 0.f};

  // prologue: fill buf 0
  stage_load(0);
  stage_write(xs[0]);
  __syncthreads();

  int cur = 0;
  for (int kc = 0; kc < NKC; ++kc) {
    const bool more = (kc + 1 < NKC);
    if (more) stage_load(kc + 1);        // issue early; latency hides under MFMA
    const short* bufc = xs[cur];

#pragma unroll
    for (int dc = 0; dc < 3; ++dc) {
      // x frags: 10 rows cover (nf 0..7) + (dr 0..2) for this wave's 8-row group
      short8 xf[10];
#pragma unroll
      for (int rr = 0; rr < 10; ++rr)
        xf[rr] = *(const short8*)(bufc + ((8 * wy + rr) * 18 + l15 + dc) * 40 + l4 * 8);
#pragma unroll
      for (int dr = 0; dr < 3; ++dr) {
        short8 wf[4];
        const short* wp = wdt + ((((size_t)b * 9 + dr * 3 + dc) * (CI / 8) + kc * 4 + l4) * CO + cob + l15) * 8;
#pragma unroll
        for (int cf = 0; cf < 4; ++cf)
          wf[cf] = *(const short8*)(wp + cf * 128);
#pragma unroll
        for (int nf = 0; nf < 8; ++nf)
#pragma unroll
          for (int cf = 0; cf < 4; ++cf) {
            if (MODE == 0)
              acc[nf][cf] = __builtin_amdgcn_mfma_f32_16x16x32_bf16(
                  xf[nf + dr], wf[cf], acc[nf][cf], 0, 0, 0);
            else
              acc[nf][cf] = __builtin_amdgcn_mfma_f32_16x16x32_bf16(
                  wf[cf], xf[nf + dr], acc[nf][cf], 0, 0, 0);
          }
      }
    }

    if (more) stage_write(xs[cur ^ 1]);  // compiler inserts vmcnt wait on pre[]
    __syncthreads();                     // one barrier per kc
    cur ^= 1;
  }

  if (MODE == 0) {
    // D[m=px-col][n=co]: lane holds col = l4*4+r, co = l15 (16 lanes = 32B contig)
    float gs[4];
#pragma unroll
    for (int cf = 0; cf < 4; ++cf) gs[cf] = 0.f;
#pragma unroll
    for (int cf = 0; cf < 4; ++cf) {
      float bs = bias[cob + cf * 16 + l15];
#pragma unroll
      for (int nf = 0; nf < 8; ++nf) {
        int row = ty0 + 8 * wy + nf;
#pragma unroll
        for (int r = 0; r < 4; ++r) {
          int col = tx0 + l4 * 4 + r;
          float v = fmaxf(acc[nf][cf][r] + bs, 0.f);
          gs[cf] += v;
          yout_t[((size_t)b * HW + (size_t)row * W + col) * CO + cob + cf * 16 + l15] = f2bf(v);
        }
      }
    }
    // per-wave GAP partials: reduce over l4 (same co = cob+cf*16+l15), no atomics
#pragma unroll
    for (int cf = 0; cf < 4; ++cf) {
      gs[cf] += __shfl_xor(gs[cf], 16, 64);
      gs[cf] += __shfl_xor(gs[cf], 32, 64);
    }
    if (l4 == 0) {
      int pslot = blockIdx.x * 2 + wy;   // 64 px-blocks x 2 row-groups = 128 slots
#pragma unroll
      for (int cf = 0; cf < 4; ++cf)
        gpart2[((size_t)b * 256 + cob + cf * 16 + l15) * 256 + pslot] = gs[cf];
    }
  } else {
    // D[m=co][n=px-col]: lane holds co = cf*16 + l4*4 + r, col = l15; fp32 NCHW
#pragma unroll
    for (int cf = 0; cf < 4; ++cf) {
#pragma unroll
      for (int r = 0; r < 4; ++r) {
        int co = cob + cf * 16 + l4 * 4 + r;
        float bs = bias[co];
#pragma unroll
        for (int nf = 0; nf < 8; ++nf) {
          int row = ty0 + 8 * wy + nf;
          int col = tx0 + l15;
          yout_f[((size_t)b * CO + co) * HW + (size_t)row * W + col] =
              fmaxf(acc[nf][cf][r] + bs, 0.f);
        }
      }
    }
  }
}

extern "C" void kernel_launch(void* const* d_in, const int* in_sizes, int n_in,
                              void* d_out, int out_size, void* d_ws, size_t ws_size,
                              hipStream_t stream) {
  const int B = 16, CIN = 128, COUT = 256, H = 128, W = 128, HW = H * W;

  const float* x    = (const float*)d_in[0];
  const float* w1fr = (const float*)d_in[1];
  const float* w1fi = (const float*)d_in[2];
  const float* b1   = (const float*)d_in[3];
  const float* a1w1 = (const float*)d_in[4];
  const float* a1b1 = (const float*)d_in[5];
  const float* a1w2 = (const float*)d_in[6];
  const float* a1b2 = (const float*)d_in[7];
  const float* w2fr = (const float*)d_in[8];
  const float* w2fi = (const float*)d_in[9];
  const float* b2   = (const float*)d_in[10];
  const float* a2w1 = (const float*)d_in[11];
  const float* a2b1 = (const float*)d_in[12];
  const float* a2w2 = (const float*)d_in[13];
  const float* a2b2 = (const float*)d_in[14];
  float* outf = (float*)d_out;

  // d_out scratch (all dead before conv2 overwrites d_out):
  short* xt     = (short*)d_out;                              // 67,108,864 B
  float* gpart1 = (float*)((char*)d_out + 67108864);          //  2,097,152 B (B*CIN x 256)
  float* gpart2 = (float*)((char*)d_out + 69206016);          //  4,194,304 B (B*COUT x 256)

  char* wsb = (char*)d_ws;
  short* y1t  = (short*)wsb;                                   // 134,217,728 B
  short* wdt  = (short*)(wsb + 134217728);                     //  18,874,368 B
  float* gap1 = (float*)(wsb + 134217728 + 18874368);          //       8,192 B
  float* gap2 = (float*)(wsb + 134217728 + 18874368 + 8192);   //      16,384 B
  float* attn = (float*)(wsb + 134217728 + 18874368 + 8192 + 16384); // 256 B

  const float gsc = 1.f / (float)HW;

  // ---- layer 1 ----
  transpose_bf16_kernel<<<dim3(HW / 64, CIN / 32, B), 256, 0, stream>>>(x, xt, CIN, gpart1);
  gap_reduce_kernel<<<(B * CIN) / 4, 256, 0, stream>>>(gpart1, gap1, gsc, 64);
  fd_attn_kernel<<<B, 64, 0, stream>>>(gap1, CIN, CIN / 4, a1w1, a1b1, a1w2, a1b2, attn);
  fd_synth_t_kernel<<<(B * CIN * COUT) / 256, 256, 0, stream>>>(w1fr, w1fi, attn, wdt, B, COUT, CIN);
  conv_mfma_kernel<128, 0><<<dim3(64, 1, 16), 512, 0, stream>>>(xt, wdt, b1, y1t, nullptr, gpart2);

  // ---- layer 2 ----
  gap_reduce_kernel<<<(B * COUT) / 4, 256, 0, stream>>>(gpart2, gap2, gsc, 32);
  fd_attn_kernel<<<B, 64, 0, stream>>>(gap2, COUT, COUT / 4, a2w1, a2b1, a2w2, a2b2, attn);
  fd_synth_t_kernel<<<(B * COUT * COUT) / 256, 256, 0, stream>>>(w2fr, w2fi, attn, wdt, B, COUT, COUT);
  conv_mfma_kernel<256, 1><<<dim3(64, 1, 16), 512, 0, stream>>>(y1t, wdt, b2, nullptr, outf, nullptr);
}